// Round 14
// baseline (8047.231 us; speedup 1.0000x reference)
//
#include <hip/hip_runtime.h>
#include <stdint.h>

#define RB 8
#define QN 4096
#define DN 512
#define LN 256
#define NITERS 25

typedef double f64x4 __attribute__((ext_vector_type(4)));

// ---------------- Threefry-2x32 (exact JAX algorithm) ----------------
__device__ __forceinline__ void tf2x32(uint32_t k0, uint32_t k1,
                                       uint32_t x0, uint32_t x1,
                                       uint32_t& y0, uint32_t& y1) {
  uint32_t ks2 = k0 ^ k1 ^ 0x1BD11BDAu;
#define TFR(r) { x0 += x1; x1 = (x1 << (r)) | (x1 >> (32 - (r))); x1 ^= x0; }
  x0 += k0; x1 += k1;
  TFR(13) TFR(15) TFR(26) TFR(6)   x0 += k1;  x1 += ks2 + 1u;
  TFR(17) TFR(29) TFR(16) TFR(24)  x0 += ks2; x1 += k0 + 2u;
  TFR(13) TFR(15) TFR(26) TFR(6)   x0 += k0;  x1 += k1 + 3u;
  TFR(17) TFR(29) TFR(16) TFR(24)  x0 += k1;  x1 += ks2 + 4u;
  TFR(13) TFR(15) TFR(26) TFR(6)   x0 += ks2; x1 += k0 + 5u;
#undef TFR
  y0 = x0; y1 = x1;
}

// jax.random.permutation under jax_threefry_partitionable=True (verified r2->r3)
__global__ __launch_bounds__(1024) void k_init(const float* __restrict__ x,
                                               float* __restrict__ centers) {
  __shared__ unsigned long long comp[QN];
  __shared__ unsigned short perm[QN];
  __shared__ unsigned short ptmp[QN];
  const int b = blockIdx.x, t = threadIdx.x;

  uint32_t kb0, kb1;
  tf2x32(0u, 42u, 0u, (uint32_t)b, kb0, kb1);

  for (int i = t; i < QN; i += 1024) perm[i] = (unsigned short)i;
  __syncthreads();

  for (int round = 0; round < 2; ++round) {
    uint32_t nk0, nk1, sk0, sk1;
    tf2x32(kb0, kb1, 0u, 0u, nk0, nk1);
    tf2x32(kb0, kb1, 0u, 1u, sk0, sk1);
    kb0 = nk0; kb1 = nk1;
    for (int i = t; i < QN; i += 1024) {
      uint32_t y0, y1;
      tf2x32(sk0, sk1, 0u, (uint32_t)i, y0, y1);
      uint32_t bits = y0 ^ y1;
      comp[i] = ((unsigned long long)bits << 32) | (unsigned)i;
    }
    __syncthreads();
    for (int k = 2; k <= QN; k <<= 1) {
      for (int j = k >> 1; j > 0; j >>= 1) {
        for (int i = t; i < QN; i += 1024) {
          int ixj = i ^ j;
          if (ixj > i) {
            unsigned long long vi = comp[i], vj = comp[ixj];
            bool up = ((i & k) == 0);
            bool sw = up ? (vi > vj) : (vi < vj);
            if (sw) { comp[i] = vj; comp[ixj] = vi; }
          }
        }
        __syncthreads();
      }
    }
    for (int i = t; i < QN; i += 1024) ptmp[i] = perm[(unsigned)(comp[i] & 0xFFFFu)];
    __syncthreads();
    for (int i = t; i < QN; i += 1024) perm[i] = ptmp[i];
    __syncthreads();
  }

  const float4* xb = (const float4*)(x + (size_t)b * QN * DN);
  float4* cb = (float4*)(centers + (size_t)b * LN * DN);
  for (int e = t; e < LN * (DN / 4); e += 1024) {
    int row = e >> 7;
    int c = e & 127;
    cb[(size_t)row * 128 + c] = xb[(size_t)perm[row] * 128 + c];
  }
}

// fp64 row sum-of-squares
__global__ __launch_bounds__(256) void k_rowsq_d(const float* __restrict__ a,
                                                 double* __restrict__ o, int nrows) {
  int w = (blockIdx.x * 256 + threadIdx.x) >> 6;
  int lane = threadIdx.x & 63;
  if (w >= nrows) return;
  const float* row = a + (size_t)w * DN;
  double s = 0.0;
  for (int i = lane; i < DN; i += 64) { double v = (double)row[i]; s = fma(v, v, s); }
#pragma unroll
  for (int off = 32; off; off >>= 1) s += __shfl_down(s, off);
  if (lane == 0) o[w] = s;
}

// ---------------- MFMA layout probe (1 wave) ----------------
//   mode 1: D[4*(lane>>4)+reg][lane&15]
//   mode 2: D[(lane>>4)+4*reg][lane&15]
//   mode 0: neither -> VALU fallback
__global__ __launch_bounds__(64) void k_probe(int* __restrict__ flag) {
  __shared__ double xT[16][17];
  __shared__ double cT[16][17];
  const int t = threadIdx.x;
  for (int i = t; i < 256; i += 64) {
    int r = i >> 4, d = i & 15;
    xT[d][r] = (double)(r * 5 + d * 3 + 1);
    cT[d][r] = (double)(r * 2 + d * 7 + 2);
  }
  __syncthreads();
  const int kg = t >> 4, li = t & 15;
  f64x4 acc = {0.0, 0.0, 0.0, 0.0};
#pragma unroll
  for (int kk = 0; kk < 4; kk++) {
    double a  = xT[kk * 4 + kg][li];
    double bv = cT[kk * 4 + kg][li];
    acc = __builtin_amdgcn_mfma_f64_16x16x4f64(a, bv, acc, 0, 0, 0);
  }
  bool ok1 = true, ok2 = true;
#pragma unroll
  for (int d = 0; d < 4; d++) {
    int q1 = kg * 4 + d;
    int q2 = kg + 4 * d;
    double ref1 = 0.0, ref2 = 0.0;
    for (int dd = 0; dd < 16; dd++) {
      ref1 += xT[dd][q1] * cT[dd][li];
      ref2 += xT[dd][q2] * cT[dd][li];
    }
    ok1 = ok1 && (acc[d] == ref1);
    ok2 = ok2 && (acc[d] == ref2);
  }
  unsigned long long v1 = __ballot(ok1);
  unsigned long long v2 = __ballot(ok2);
  if (t == 0) *flag = (v1 == ~0ull) ? 1 : ((v2 == ~0ull) ? 2 : 0);
}

#define QT 64
// MFMA-path pitches: x fp64 transposed [16][69] (conflict-free, r11-verified);
// c fp32 ROW-major [256][20] (pitch 20 floats = 80B, 16B-aligned float4 rows;
// frag-read bank occupancy <= 2-way = free). c converts to double at read --
// exact widening, same MFMA order => W bit-identical to r11.
#define XPD 69
#define CPF 20
// VALU-path pitches (r5-verified)
#define DK 16
#define XLD 82
#define CLDf 260
__device__ __forceinline__ int grow(int q) { return q + ((q >> 3) << 1); }

// Arena (doubles): MFMA 1104 + 2560 + 320 + 320 = 4304; VALU 6048. Max 6048.
#define ARENA_D 6048

// dist -> softmax -> W; 256 threads, mode-gated MFMA path (r11 tile 64q x 256l).
__global__ __launch_bounds__(256, 2) void k_assign(const float* __restrict__ x,
                                                   const float* __restrict__ centers,
                                                   const double* __restrict__ csqd,
                                                   float* __restrict__ W,
                                                   const int* __restrict__ flag) {
  __shared__ double arena[ARENA_D];
  const int mode = *flag;
  const int b = blockIdx.y, q0 = blockIdx.x * QT, t = threadIdx.x;
  const float* xb = x + ((size_t)b * QN + q0) * DN;
  const float* cb = centers + (size_t)b * LN * DN;
  const int xrow = t >> 2, xc4 = t & 3;

  if (mode != 0) {
    // ---------------- MFMA path ----------------
    double (*xT)[XPD]  = (double(*)[XPD])arena;                       // [16][69]
    float  (*csF)[CPF] = (float(*)[CPF])(arena + 16 * XPD);           // [256][20]
    double (*redm)[5]  = (double(*)[5])(arena + 1104 + 2560);         // [64][5]
    double (*reds)[5]  = (double(*)[5])(arena + 1104 + 2560 + 320);
    const int w = t >> 6, lane = t & 63;
    const int kg = lane >> 4, li = lane & 15;

    f64x4 acc[4][4];
#pragma unroll
    for (int i = 0; i < 4; i++)
#pragma unroll
      for (int j = 0; j < 4; j++) acc[i][j] = (f64x4){0.0, 0.0, 0.0, 0.0};

    float4 gx, gc[4];
    gx = *(const float4*)(xb + (size_t)xrow * DN + xc4 * 4);
#pragma unroll
    for (int i = 0; i < 4; i++) {
      int f = t + 256 * i; int row = f >> 2, c4 = f & 3;
      gc[i] = *(const float4*)(cb + (size_t)row * DN + c4 * 4);
    }

    for (int d0 = 0; d0 < DN; d0 += 16) {
      xT[xc4 * 4 + 0][xrow] = (double)gx.x;
      xT[xc4 * 4 + 1][xrow] = (double)gx.y;
      xT[xc4 * 4 + 2][xrow] = (double)gx.z;
      xT[xc4 * 4 + 3][xrow] = (double)gx.w;
#pragma unroll
      for (int i = 0; i < 4; i++) {
        int f = t + 256 * i; int row = f >> 2, c4 = f & 3;
        *(float4*)&csF[row][c4 * 4] = gc[i];
      }
      __syncthreads();
      if (d0 + 16 < DN) {
        gx = *(const float4*)(xb + (size_t)xrow * DN + (d0 + 16) + xc4 * 4);
#pragma unroll
        for (int i = 0; i < 4; i++) {
          int f = t + 256 * i; int row = f >> 2, c4 = f & 3;
          gc[i] = *(const float4*)(cb + (size_t)row * DN + (d0 + 16) + c4 * 4);
        }
      }
      // register-double-buffered fragment pipeline
      double a0[4], b0[4];
#pragma unroll
      for (int qt = 0; qt < 4; qt++) a0[qt] = xT[kg][qt * 16 + li];
#pragma unroll
      for (int lt = 0; lt < 4; lt++) b0[lt] = (double)csF[w * 64 + lt * 16 + li][kg];
#pragma unroll
      for (int kk = 0; kk < 4; kk++) {
        double a1[4], b1[4];
        if (kk + 1 < 4) {
#pragma unroll
          for (int qt = 0; qt < 4; qt++) a1[qt] = xT[(kk + 1) * 4 + kg][qt * 16 + li];
#pragma unroll
          for (int lt = 0; lt < 4; lt++) b1[lt] = (double)csF[w * 64 + lt * 16 + li][(kk + 1) * 4 + kg];
        }
#pragma unroll
        for (int qt = 0; qt < 4; qt++)
#pragma unroll
          for (int lt = 0; lt < 4; lt++)
            acc[qt][lt] = __builtin_amdgcn_mfma_f64_16x16x4f64(a0[qt], b0[lt], acc[qt][lt], 0, 0, 0);
        if (kk + 1 < 4) {
#pragma unroll
          for (int qt = 0; qt < 4; qt++) a0[qt] = a1[qt];
#pragma unroll
          for (int lt = 0; lt < 4; lt++) b0[lt] = b1[lt];
        }
      }
      __syncthreads();
    }

    // epilogue: logits, cross-wave softmax (l split across waves)
    double csqv[4];
#pragma unroll
    for (int lt = 0; lt < 4; lt++) csqv[lt] = csqd[b * LN + w * 64 + lt * 16 + li];

    double rm[4][4];
#pragma unroll
    for (int qt = 0; qt < 4; qt++)
#pragma unroll
      for (int d = 0; d < 4; d++) {
        double m = -1e300;
#pragma unroll
        for (int lt = 0; lt < 4; lt++) {
          double lg = -5.0 * (csqv[lt] - 2.0 * acc[qt][lt][d]);
          acc[qt][lt][d] = lg;
          m = fmax(m, lg);
        }
        rm[qt][d] = m;
      }
#pragma unroll
    for (int off = 1; off < 16; off <<= 1)
#pragma unroll
      for (int qt = 0; qt < 4; qt++)
#pragma unroll
        for (int d = 0; d < 4; d++) rm[qt][d] = fmax(rm[qt][d], __shfl_xor(rm[qt][d], off, 64));
    if (li == 0) {
#pragma unroll
      for (int qt = 0; qt < 4; qt++)
#pragma unroll
        for (int d = 0; d < 4; d++) {
          int qr = qt * 16 + ((mode == 1) ? (kg * 4 + d) : (kg + 4 * d));
          redm[qr][w] = rm[qt][d];
        }
    }
    __syncthreads();
#pragma unroll
    for (int qt = 0; qt < 4; qt++)
#pragma unroll
      for (int d = 0; d < 4; d++) {
        int qr = qt * 16 + ((mode == 1) ? (kg * 4 + d) : (kg + 4 * d));
        rm[qt][d] = fmax(fmax(redm[qr][0], redm[qr][1]), fmax(redm[qr][2], redm[qr][3]));
      }
    double sv[4][4];
#pragma unroll
    for (int qt = 0; qt < 4; qt++)
#pragma unroll
      for (int d = 0; d < 4; d++) {
        double s = 0.0;
#pragma unroll
        for (int lt = 0; lt < 4; lt++) {
          double e = exp(acc[qt][lt][d] - rm[qt][d]);
          acc[qt][lt][d] = e;
          s += e;
        }
        sv[qt][d] = s;
      }
#pragma unroll
    for (int off = 1; off < 16; off <<= 1)
#pragma unroll
      for (int qt = 0; qt < 4; qt++)
#pragma unroll
        for (int d = 0; d < 4; d++) sv[qt][d] += __shfl_xor(sv[qt][d], off, 64);
    if (li == 0) {
#pragma unroll
      for (int qt = 0; qt < 4; qt++)
#pragma unroll
        for (int d = 0; d < 4; d++) {
          int qr = qt * 16 + ((mode == 1) ? (kg * 4 + d) : (kg + 4 * d));
          reds[qr][w] = sv[qt][d];
        }
    }
    __syncthreads();
#pragma unroll
    for (int qt = 0; qt < 4; qt++)
#pragma unroll
      for (int d = 0; d < 4; d++) {
        int qr = qt * 16 + ((mode == 1) ? (kg * 4 + d) : (kg + 4 * d));
        double tot = reds[qr][0] + reds[qr][1] + reds[qr][2] + reds[qr][3];
        double inv = 1.0 / tot;
        float* wr = W + ((size_t)b * QN + q0 + qr) * LN + w * 64 + li;
#pragma unroll
        for (int lt = 0; lt < 4; lt++)
          wr[lt * 16] = (float)(acc[qt][lt][d] * inv);
      }
  } else {
    // ---------------- VALU fallback (r5-verified) ----------------
    double (*xsD)[XLD]   = (double(*)[XLD])arena;
    float  (*csFv)[CLDf] = (float(*)[CLDf])(arena + 16 * XLD);
    double (*red)[33]    = (double(*)[33])(arena + 16 * XLD + (16 * CLDf) / 2);
    const int rg = t & 7, cg = t >> 3;
    double acc[8][8];
#pragma unroll
    for (int i = 0; i < 8; i++)
#pragma unroll
      for (int j = 0; j < 8; j++) acc[i][j] = 0.0;

    const int xg = grow(xrow);
    float4 gx, gc[4];
    gx = *(const float4*)(xb + (size_t)xrow * DN + xc4 * 4);
#pragma unroll
    for (int i = 0; i < 4; i++) {
      int f = t + 256 * i; int row = f >> 2, c4 = f & 3;
      gc[i] = *(const float4*)(cb + (size_t)row * DN + c4 * 4);
    }

    for (int d0 = 0; d0 < DN; d0 += DK) {
      xsD[xc4 * 4 + 0][xg] = (double)gx.x; xsD[xc4 * 4 + 1][xg] = (double)gx.y;
      xsD[xc4 * 4 + 2][xg] = (double)gx.z; xsD[xc4 * 4 + 3][xg] = (double)gx.w;
#pragma unroll
      for (int i = 0; i < 4; i++) {
        int f = t + 256 * i; int row = f >> 2, c4 = f & 3;
        csFv[c4 * 4 + 0][row] = gc[i].x; csFv[c4 * 4 + 1][row] = gc[i].y;
        csFv[c4 * 4 + 2][row] = gc[i].z; csFv[c4 * 4 + 3][row] = gc[i].w;
      }
      __syncthreads();
      if (d0 + DK < DN) {
        gx = *(const float4*)(xb + (size_t)xrow * DN + (d0 + DK) + xc4 * 4);
#pragma unroll
        for (int i = 0; i < 4; i++) {
          int f = t + 256 * i; int row = f >> 2, c4 = f & 3;
          gc[i] = *(const float4*)(cb + (size_t)row * DN + (d0 + DK) + c4 * 4);
        }
      }
      double xva[8]; float4 ca0, ca1;
#pragma unroll
      for (int j = 0; j < 8; j++) xva[j] = xsD[0][rg * 10 + j];
      ca0 = *(const float4*)&csFv[0][cg * 8];
      ca1 = *(const float4*)&csFv[0][cg * 8 + 4];
#pragma unroll
      for (int k = 0; k < DK; k++) {
        double xvb[8]; float4 cb0, cb1;
        if (k + 1 < DK) {
#pragma unroll
          for (int j = 0; j < 8; j++) xvb[j] = xsD[k + 1][rg * 10 + j];
          cb0 = *(const float4*)&csFv[k + 1][cg * 8];
          cb1 = *(const float4*)&csFv[k + 1][cg * 8 + 4];
        }
        double cv[8] = {(double)ca0.x, (double)ca0.y, (double)ca0.z, (double)ca0.w,
                        (double)ca1.x, (double)ca1.y, (double)ca1.z, (double)ca1.w};
#pragma unroll
        for (int i = 0; i < 8; i++)
#pragma unroll
          for (int j = 0; j < 8; j++)
            acc[i][j] = fma(xva[i], cv[j], acc[i][j]);
        if (k + 1 < DK) {
#pragma unroll
          for (int j = 0; j < 8; j++) xva[j] = xvb[j];
          ca0 = cb0; ca1 = cb1;
        }
      }
      __syncthreads();
    }

    double csqv[8];
#pragma unroll
    for (int j = 0; j < 8; j++) csqv[j] = csqd[b * LN + cg * 8 + j];

    double lmax[8];
#pragma unroll
    for (int i = 0; i < 8; i++) {
      double m = -1e300;
#pragma unroll
      for (int j = 0; j < 8; j++) {
        double lg = -5.0 * (csqv[j] - 2.0 * acc[i][j]);
        acc[i][j] = lg;
        m = fmax(m, lg);
      }
      lmax[i] = m;
    }
#pragma unroll
    for (int i = 0; i < 8; i++) red[rg * 8 + i][cg] = lmax[i];
    __syncthreads();
    double rmax[8];
#pragma unroll
    for (int i = 0; i < 8; i++) {
      double m = -1e300;
      for (int c = 0; c < 32; c++) m = fmax(m, red[rg * 8 + i][c]);
      rmax[i] = m;
    }
    __syncthreads();
#pragma unroll
    for (int i = 0; i < 8; i++) {
      double s = 0.0;
#pragma unroll
      for (int j = 0; j < 8; j++) {
        double e = exp(acc[i][j] - rmax[i]);
        acc[i][j] = e;
        s += e;
      }
      red[rg * 8 + i][cg] = s;
    }
    __syncthreads();
#pragma unroll
    for (int i = 0; i < 8; i++) {
      double s = 0.0;
      for (int c = 0; c < 32; c++) s += red[rg * 8 + i][c];
      float* wrow = W + ((size_t)b * QN + q0 + rg * 8 + i) * LN + cg * 8;
      float4 v0 = make_float4((float)(acc[i][0] / s), (float)(acc[i][1] / s),
                              (float)(acc[i][2] / s), (float)(acc[i][3] / s));
      float4 v1 = make_float4((float)(acc[i][4] / s), (float)(acc[i][5] / s),
                              (float)(acc[i][6] / s), (float)(acc[i][7] / s));
      *(float4*)wrow = v0;
      *(float4*)(wrow + 4) = v1;
    }
  }
}

// ---------------- split-K centroid update (r11-verified NCH=8) ----------------
#define NCH 8
#define CHQ (QN / NCH)   // 512
#define UKQ 16

__global__ __launch_bounds__(256, 3) void k_update_split(
    const float* __restrict__ W, const float* __restrict__ x,
    float* __restrict__ P, float* __restrict__ dsum) {
  __shared__ float wT[UKQ][132];
  __shared__ float xT[UKQ][132];
  const int b = blockIdx.z;
  const int s = blockIdx.y;
  const int lt = (blockIdx.x >> 2) * 128;
  const int dt = (blockIdx.x & 3) * 128;
  const int t = threadIdx.x;
  const int tr = t >> 4, tc = t & 15;
  float acc[8][8];
#pragma unroll
  for (int i = 0; i < 8; i++)
#pragma unroll
    for (int j = 0; j < 8; j++) acc[i][j] = 0.f;
  float dsm[8] = {0, 0, 0, 0, 0, 0, 0, 0};

  const float* Wb = W + ((size_t)b * QN + (size_t)s * CHQ) * LN + lt;
  const float* xb = x + ((size_t)b * QN + (size_t)s * CHQ) * DN + dt;

  float4 gw[2], gx2[2];
#pragma unroll
  for (int i = 0; i < 2; i++) {
    int f = t + 256 * i; int row = f >> 5, c = f & 31;
    gw[i]  = *(const float4*)(Wb + (size_t)row * LN + c * 4);
    gx2[i] = *(const float4*)(xb + (size_t)row * DN + c * 4);
  }

  for (int k0 = 0; k0 < CHQ; k0 += UKQ) {
#pragma unroll
    for (int i = 0; i < 2; i++) {
      int f = t + 256 * i; int row = f >> 5, c = f & 31;
      *(float4*)&wT[row][c * 4] = gw[i];
      *(float4*)&xT[row][c * 4] = gx2[i];
    }
    __syncthreads();
    if (k0 + UKQ < CHQ) {
#pragma unroll
      for (int i = 0; i < 2; i++) {
        int f = t + 256 * i; int row = f >> 5, c = f & 31;
        gw[i]  = *(const float4*)(Wb + (size_t)(k0 + UKQ + row) * LN + c * 4);
        gx2[i] = *(const float4*)(xb + (size_t)(k0 + UKQ + row) * DN + c * 4);
      }
    }
#pragma unroll
    for (int k = 0; k < UKQ; k++) {
      float4 w0 = *(const float4*)&wT[k][tr * 4];
      float4 w1 = *(const float4*)&wT[k][64 + tr * 4];
      float4 x0 = *(const float4*)&xT[k][tc * 4];
      float4 x1 = *(const float4*)&xT[k][64 + tc * 4];
      float wf[8] = {w0.x, w0.y, w0.z, w0.w, w1.x, w1.y, w1.z, w1.w};
      float xf[8] = {x0.x, x0.y, x0.z, x0.w, x1.x, x1.y, x1.z, x1.w};
#pragma unroll
      for (int i = 0; i < 8; i++) {
        dsm[i] += wf[i];
#pragma unroll
        for (int j = 0; j < 8; j++) acc[i][j] = fmaf(wf[i], xf[j], acc[i][j]);
      }
    }
    __syncthreads();
  }

#pragma unroll
  for (int i = 0; i < 8; i++) {
    int l = lt + ((i < 4) ? (tr * 4 + i) : (64 + tr * 4 + i - 4));
    float* prow = P + (((size_t)s * RB + b) * LN + l) * DN + dt;
    *(float4*)(prow + tc * 4)      = make_float4(acc[i][0], acc[i][1], acc[i][2], acc[i][3]);
    *(float4*)(prow + 64 + tc * 4) = make_float4(acc[i][4], acc[i][5], acc[i][6], acc[i][7]);
    if (tc == 0) dsum[((size_t)s * RB + b) * LN + l] = dsm[i];
  }
}

// Cnew = (sum_s P) / (sum_s dsum + eps); fused fp64 row sumsq -> csqd
__global__ __launch_bounds__(128) void k_reduce(const float* __restrict__ P,
                                                const float* __restrict__ dsum,
                                                float* __restrict__ cnew,
                                                double* __restrict__ csqd) {
  const int row = blockIdx.x;          // b*LN + l
  const int b = row >> 8, l = row & 255;
  const int t = threadIdx.x;
  float dn = 0.f;
#pragma unroll
  for (int s = 0; s < NCH; s++) dn += dsum[((size_t)s * RB + b) * LN + l];
  float den = dn + 1e-9f;
  float4 v = make_float4(0.f, 0.f, 0.f, 0.f);
#pragma unroll
  for (int s = 0; s < NCH; s++) {
    float4 p = *(const float4*)(P + (((size_t)s * RB + b) * LN + l) * DN + t * 4);
    v.x += p.x; v.y += p.y; v.z += p.z; v.w += p.w;
  }
  float4 o = make_float4(v.x / den, v.y / den, v.z / den, v.w / den);
  *(float4*)(cnew + ((size_t)b * LN + l) * DN + t * 4) = o;
  double sq = (double)o.x * o.x + (double)o.y * o.y +
              (double)o.z * o.z + (double)o.w * o.w;
#pragma unroll
  for (int off = 32; off; off >>= 1) sq += __shfl_down(sq, off);
  __shared__ double sred[2];
  if ((t & 63) == 0) sred[t >> 6] = sq;
  __syncthreads();
  if (t == 0) csqd[row] = sred[0] + sred[1];
}

// monolithic fallback update (used when ws is small)
#define LT 64
#define DT 64
#define KQ 32
__global__ __launch_bounds__(256) void k_update_mono(const float* __restrict__ W,
                                                     const float* __restrict__ x,
                                                     float* __restrict__ cnew) {
  __shared__ float wT[KQ][LT + 4];
  __shared__ float xT[KQ][DT + 4];
  const int b = blockIdx.z;
  const int l0 = blockIdx.x * LT;
  const int d0 = blockIdx.y * DT;
  const int t = threadIdx.x;
  const int rg = t & 15;
  const int cg = t >> 4;
  float acc[4][4];
#pragma unroll
  for (int i = 0; i < 4; i++)
#pragma unroll
    for (int j = 0; j < 4; j++) acc[i][j] = 0.f;
  float dsm[4] = {0.f, 0.f, 0.f, 0.f};
  const float* Wb = W + (size_t)b * QN * LN;
  const float* xb = x + (size_t)b * QN * DN;
  for (int k0 = 0; k0 < QN; k0 += KQ) {
#pragma unroll
    for (int i = 0; i < 2; i++) {
      int f = t + 256 * i;
      int row = f >> 4, c4 = f & 15;
      *(float4*)&wT[row][c4 * 4] = *(const float4*)(Wb + (size_t)(k0 + row) * LN + l0 + c4 * 4);
    }
#pragma unroll
    for (int i = 0; i < 2; i++) {
      int f = t + 256 * i;
      int row = f >> 4, c4 = f & 15;
      *(float4*)&xT[row][c4 * 4] = *(const float4*)(xb + (size_t)(k0 + row) * DN + d0 + c4 * 4);
    }
    __syncthreads();
#pragma unroll
    for (int k = 0; k < KQ; k++) {
      float wf[4], xf[4];
      *(float4*)wf = *(const float4*)&wT[k][rg * 4];
      *(float4*)xf = *(const float4*)&xT[k][cg * 4];
#pragma unroll
      for (int i = 0; i < 4; i++) {
        dsm[i] += wf[i];
#pragma unroll
        for (int j = 0; j < 4; j++) acc[i][j] = fmaf(wf[i], xf[j], acc[i][j]);
      }
    }
    __syncthreads();
  }
#pragma unroll
  for (int i = 0; i < 4; i++) {
    float den = dsm[i] + 1e-9f;
    *(float4*)(cnew + ((size_t)b * LN + l0 + rg * 4 + i) * DN + d0 + cg * 4) =
        make_float4(acc[i][0] / den, acc[i][1] / den, acc[i][2] / den, acc[i][3] / den);
  }
}

// fp64 dist -> argmin -> gather; 256-thread MFMA path (c fp32) + VALU fallback.
__global__ __launch_bounds__(256, 2) void k_final(const float* __restrict__ x,
                                                  const float* __restrict__ centers,
                                                  const double* __restrict__ csqd,
                                                  float* __restrict__ out,
                                                  const int* __restrict__ flag) {
  __shared__ double arena[ARENA_D];
  const int mode = *flag;
  const int b = blockIdx.y, q0 = blockIdx.x * QT, t = threadIdx.x;
  const float* xb = x + ((size_t)b * QN + q0) * DN;
  const float* cb = centers + (size_t)b * LN * DN;
  const int xrow = t >> 2, xc4 = t & 3;

  if (mode != 0) {
    // ---------------- MFMA path ----------------
    double (*xT)[XPD]  = (double(*)[XPD])arena;
    float  (*csF)[CPF] = (float(*)[CPF])(arena + 16 * XPD);
    double (*redv)[5]  = (double(*)[5])(arena + 1104 + 2560);           // [64][5]
    int*    redi       = (int*)(arena + 1104 + 2560 + 320);             // [64][5]
    unsigned short* labels = (unsigned short*)(arena + 1104 + 2560 + 480);
    const int w = t >> 6, lane = t & 63;
    const int kg = lane >> 4, li = lane & 15;

    f64x4 acc[4][4];
#pragma unroll
    for (int i = 0; i < 4; i++)
#pragma unroll
      for (int j = 0; j < 4; j++) acc[i][j] = (f64x4){0.0, 0.0, 0.0, 0.0};

    float4 gx, gc[4];
    gx = *(const float4*)(xb + (size_t)xrow * DN + xc4 * 4);
#pragma unroll
    for (int i = 0; i < 4; i++) {
      int f = t + 256 * i; int row = f >> 2, c4 = f & 3;
      gc[i] = *(const float4*)(cb + (size_t)row * DN + c4 * 4);
    }

    for (int d0 = 0; d0 < DN; d0 += 16) {
      xT[xc4 * 4 + 0][xrow] = (double)gx.x;
      xT[xc4 * 4 + 1][xrow] = (double)gx.y;
      xT[xc4 * 4 + 2][xrow] = (double)gx.z;
      xT[xc4 * 4 + 3][xrow] = (double)gx.w;
#pragma unroll
      for (int i = 0; i < 4; i++) {
        int f = t + 256 * i; int row = f >> 2, c4 = f & 3;
        *(float4*)&csF[row][c4 * 4] = gc[i];
      }
      __syncthreads();
      if (d0 + 16 < DN) {
        gx = *(const float4*)(xb + (size_t)xrow * DN + (d0 + 16) + xc4 * 4);
#pragma unroll
        for (int i = 0; i < 4; i++) {
          int f = t + 256 * i; int row = f >> 2, c4 = f & 3;
          gc[i] = *(const float4*)(cb + (size_t)row * DN + (d0 + 16) + c4 * 4);
        }
      }
      double a0[4], b0[4];
#pragma unroll
      for (int qt = 0; qt < 4; qt++) a0[qt] = xT[kg][qt * 16 + li];
#pragma unroll
      for (int lt = 0; lt < 4; lt++) b0[lt] = (double)csF[w * 64 + lt * 16 + li][kg];
#pragma unroll
      for (int kk = 0; kk < 4; kk++) {
        double a1[4], b1[4];
        if (kk + 1 < 4) {
#pragma unroll
          for (int qt = 0; qt < 4; qt++) a1[qt] = xT[(kk + 1) * 4 + kg][qt * 16 + li];
#pragma unroll
          for (int lt = 0; lt < 4; lt++) b1[lt] = (double)csF[w * 64 + lt * 16 + li][(kk + 1) * 4 + kg];
        }
#pragma unroll
        for (int qt = 0; qt < 4; qt++)
#pragma unroll
          for (int lt = 0; lt < 4; lt++)
            acc[qt][lt] = __builtin_amdgcn_mfma_f64_16x16x4f64(a0[qt], b0[lt], acc[qt][lt], 0, 0, 0);
        if (kk + 1 < 4) {
#pragma unroll
          for (int qt = 0; qt < 4; qt++) a0[qt] = a1[qt];
#pragma unroll
          for (int lt = 0; lt < 4; lt++) b0[lt] = b1[lt];
        }
      }
      __syncthreads();
    }

    // argmin epilogue: key = csq - 2*dot; first-min tie-break on l
    double csqv[4];
#pragma unroll
    for (int lt = 0; lt < 4; lt++) csqv[lt] = csqd[b * LN + w * 64 + lt * 16 + li];

    double bv[4][4]; int bi[4][4];
#pragma unroll
    for (int qt = 0; qt < 4; qt++)
#pragma unroll
      for (int d = 0; d < 4; d++) {
        double best = 1e300; int bidx = 0;
#pragma unroll
        for (int lt = 0; lt < 4; lt++) {
          double dd = csqv[lt] - 2.0 * acc[qt][lt][d];
          int l = w * 64 + lt * 16 + li;
          if (dd < best) { best = dd; bidx = l; }
        }
        bv[qt][d] = best; bi[qt][d] = bidx;
      }
#pragma unroll
    for (int off = 1; off < 16; off <<= 1)
#pragma unroll
      for (int qt = 0; qt < 4; qt++)
#pragma unroll
        for (int d = 0; d < 4; d++) {
          double ov = __shfl_xor(bv[qt][d], off, 64);
          int oi = __shfl_xor(bi[qt][d], off, 64);
          if (ov < bv[qt][d] || (ov == bv[qt][d] && oi < bi[qt][d])) {
            bv[qt][d] = ov; bi[qt][d] = oi;
          }
        }
    if (li == 0) {
#pragma unroll
      for (int qt = 0; qt < 4; qt++)
#pragma unroll
        for (int d = 0; d < 4; d++) {
          int qr = qt * 16 + ((mode == 1) ? (kg * 4 + d) : (kg + 4 * d));
          redv[qr][w] = bv[qt][d];
          redi[qr * 5 + w] = bi[qt][d];
        }
    }
    __syncthreads();
    if (t < QT) {
      double best = redv[t][0]; int bidx = redi[t * 5 + 0];
#pragma unroll
      for (int ww = 1; ww < 4; ww++) {
        double v = redv[t][ww]; int id = redi[t * 5 + ww];
        if (v < best || (v == best && id < bidx)) { best = v; bidx = id; }
      }
      labels[t] = (unsigned short)bidx;
    }
    __syncthreads();
    const float4* cb4 = (const float4*)(centers + (size_t)b * LN * DN);
    float4* ob = (float4*)(out + ((size_t)b * QN + q0) * DN);
    for (int e = t; e < QT * (DN / 4); e += 256) {
      int row = e >> 7, c = e & 127;
      ob[(size_t)row * 128 + c] = cb4[(size_t)labels[row] * 128 + c];
    }
  } else {
    // ---------------- VALU fallback (r5-verified) ----------------
    double (*xsD)[XLD]   = (double(*)[XLD])arena;
    float  (*csFv)[CLDf] = (float(*)[CLDf])(arena + 16 * XLD);
    double (*redv)[33]   = (double(*)[33])(arena + 3392);
    unsigned short* redi = (unsigned short*)(arena + 5504);
    unsigned short* labels = (unsigned short*)(arena + 6032);
    const int rg = t & 7, cg = t >> 3;
    const int xg = grow(xrow);
    double acc[8][8];
#pragma unroll
    for (int i = 0; i < 8; i++)
#pragma unroll
      for (int j = 0; j < 8; j++) acc[i][j] = 0.0;

    float4 gx, gc[4];
    gx = *(const float4*)(xb + (size_t)xrow * DN + xc4 * 4);
#pragma unroll
    for (int i = 0; i < 4; i++) {
      int f = t + 256 * i; int row = f >> 2, c4 = f & 3;
      gc[i] = *(const float4*)(cb + (size_t)row * DN + c4 * 4);
    }

    for (int d0 = 0; d0 < DN; d0 += DK) {
      xsD[xc4 * 4 + 0][xg] = (double)gx.x; xsD[xc4 * 4 + 1][xg] = (double)gx.y;
      xsD[xc4 * 4 + 2][xg] = (double)gx.z; xsD[xc4 * 4 + 3][xg] = (double)gx.w;
#pragma unroll
      for (int i = 0; i < 4; i++) {
        int f = t + 256 * i; int row = f >> 2, c4 = f & 3;
        csFv[c4 * 4 + 0][row] = gc[i].x; csFv[c4 * 4 + 1][row] = gc[i].y;
        csFv[c4 * 4 + 2][row] = gc[i].z; csFv[c4 * 4 + 3][row] = gc[i].w;
      }
      __syncthreads();
      if (d0 + DK < DN) {
        gx = *(const float4*)(xb + (size_t)xrow * DN + (d0 + DK) + xc4 * 4);
#pragma unroll
        for (int i = 0; i < 4; i++) {
          int f = t + 256 * i; int row = f >> 2, c4 = f & 3;
          gc[i] = *(const float4*)(cb + (size_t)row * DN + (d0 + DK) + c4 * 4);
        }
      }
      double xva[8]; float4 ca0, ca1;
#pragma unroll
      for (int j = 0; j < 8; j++) xva[j] = xsD[0][rg * 10 + j];
      ca0 = *(const float4*)&csFv[0][cg * 8];
      ca1 = *(const float4*)&csFv[0][cg * 8 + 4];
#pragma unroll
      for (int k = 0; k < DK; k++) {
        double xvb[8]; float4 cb0, cb1;
        if (k + 1 < DK) {
#pragma unroll
          for (int j = 0; j < 8; j++) xvb[j] = xsD[k + 1][rg * 10 + j];
          cb0 = *(const float4*)&csFv[k + 1][cg * 8];
          cb1 = *(const float4*)&csFv[k + 1][cg * 8 + 4];
        }
        double cv[8] = {(double)ca0.x, (double)ca0.y, (double)ca0.z, (double)ca0.w,
                        (double)ca1.x, (double)ca1.y, (double)ca1.z, (double)ca1.w};
#pragma unroll
        for (int i = 0; i < 8; i++)
#pragma unroll
          for (int j = 0; j < 8; j++)
            acc[i][j] = fma(xva[i], cv[j], acc[i][j]);
        if (k + 1 < DK) {
#pragma unroll
          for (int j = 0; j < 8; j++) xva[j] = xvb[j];
          ca0 = cb0; ca1 = cb1;
        }
      }
      __syncthreads();
    }

    double csqv[8];
#pragma unroll
    for (int j = 0; j < 8; j++) csqv[j] = csqd[b * LN + cg * 8 + j];

    double bv[8]; int bi[8];
#pragma unroll
    for (int i = 0; i < 8; i++) {
      bv[i] = 1e300; bi[i] = 0;
#pragma unroll
      for (int j = 0; j < 8; j++) {
        double dd = csqv[j] - 2.0 * acc[i][j];
        if (dd < bv[i]) { bv[i] = dd; bi[i] = cg * 8 + j; }
      }
    }
#pragma unroll
    for (int i = 0; i < 8; i++) {
      redv[rg * 8 + i][cg] = bv[i];
      redi[(rg * 8 + i) * 33 + cg] = (unsigned short)bi[i];
    }
    __syncthreads();
    if (t < QT) {
      double best = 1e300; int bidx = 0;
      for (int c = 0; c < 32; c++) {
        double v = redv[t][c];
        int id = redi[t * 33 + c];
        if (v < best || (v == best && id < bidx)) { best = v; bidx = id; }
      }
      labels[t] = (unsigned short)bidx;
    }
    __syncthreads();
    const float4* cb4 = (const float4*)(centers + (size_t)b * LN * DN);
    float4* ob = (float4*)(out + ((size_t)b * QN + q0) * DN);
    for (int e = t; e < QT * (DN / 4); e += 256) {
      int row = e >> 7, c = e & 127;
      ob[(size_t)row * 128 + c] = cb4[(size_t)labels[row] * 128 + c];
    }
  }
}

extern "C" void kernel_launch(void* const* d_in, const int* in_sizes, int n_in,
                              void* d_out, int out_size, void* d_ws, size_t ws_size,
                              hipStream_t stream) {
  const float* x = (const float*)d_in[0];
  float* out = (float*)d_out;

  const size_t szC    = (size_t)RB * LN * DN * sizeof(float);     // 4 MB
  const size_t szCsqD = (size_t)RB * LN * sizeof(double);         // 16 KB
  const size_t szDsum = (size_t)NCH * RB * LN * sizeof(float);    // 64 KB
  const size_t szFlag = 256;
  const size_t szW    = (size_t)RB * QN * LN * sizeof(float);     // 33.5 MB

  char* p = (char*)d_ws;
  float*  cA   = (float*)p;  p += szC;
  float*  cB   = (float*)p;  p += szC;
  double* csqd = (double*)p; p += szCsqD;
  float*  dsum = (float*)p;  p += szDsum;
  int*    flag = (int*)p;    p += szFlag;
  const bool bigws = ws_size >= 2 * szC + szCsqD + szDsum + szFlag + szW;
  float* W = bigws ? (float*)p : (float*)d_out;
  float* P = (float*)d_out;   // split-K partials live in d_out (k_final rewrites)

  k_probe<<<1, 64, 0, stream>>>(flag);
  k_init<<<RB, 1024, 0, stream>>>(x, cA);
  k_rowsq_d<<<(RB * LN) / 4, 256, 0, stream>>>(cA, csqd, RB * LN);

  float* cur = cA;
  float* nxt = cB;
  for (int it = 0; it < NITERS; ++it) {
    k_assign<<<dim3(QN / QT, RB), 256, 0, stream>>>(x, cur, csqd, W, flag);
    if (bigws) {
      k_update_split<<<dim3(8, NCH, RB), 256, 0, stream>>>(W, x, P, dsum);
      k_reduce<<<RB * LN, 128, 0, stream>>>(P, dsum, nxt, csqd);
    } else {
      k_update_mono<<<dim3(LN / LT, DN / DT, RB), 256, 0, stream>>>(W, x, nxt);
      k_rowsq_d<<<(RB * LN) / 4, 256, 0, stream>>>(nxt, csqd, RB * LN);
    }
    float* tmp = cur; cur = nxt; nxt = tmp;
  }
  k_final<<<dim3(QN / QT, RB), 256, 0, stream>>>(x, cur, csqd, out, flag);
}

// Round 15
// 7583.273 us; speedup vs baseline: 1.0612x; 1.0612x over previous
//
#include <hip/hip_runtime.h>
#include <stdint.h>

#define RB 8
#define QN 4096
#define DN 512
#define LN 256
#define NITERS 25

typedef double f64x4 __attribute__((ext_vector_type(4)));

// ---------------- Threefry-2x32 (exact JAX algorithm) ----------------
__device__ __forceinline__ void tf2x32(uint32_t k0, uint32_t k1,
                                       uint32_t x0, uint32_t x1,
                                       uint32_t& y0, uint32_t& y1) {
  uint32_t ks2 = k0 ^ k1 ^ 0x1BD11BDAu;
#define TFR(r) { x0 += x1; x1 = (x1 << (r)) | (x1 >> (32 - (r))); x1 ^= x0; }
  x0 += k0; x1 += k1;
  TFR(13) TFR(15) TFR(26) TFR(6)   x0 += k1;  x1 += ks2 + 1u;
  TFR(17) TFR(29) TFR(16) TFR(24)  x0 += ks2; x1 += k0 + 2u;
  TFR(13) TFR(15) TFR(26) TFR(6)   x0 += k0;  x1 += k1 + 3u;
  TFR(17) TFR(29) TFR(16) TFR(24)  x0 += k1;  x1 += ks2 + 4u;
  TFR(13) TFR(15) TFR(26) TFR(6)   x0 += ks2; x1 += k0 + 5u;
#undef TFR
  y0 = x0; y1 = x1;
}

// jax.random.permutation under jax_threefry_partitionable=True (verified r2->r3)
__global__ __launch_bounds__(1024) void k_init(const float* __restrict__ x,
                                               float* __restrict__ centers) {
  __shared__ unsigned long long comp[QN];
  __shared__ unsigned short perm[QN];
  __shared__ unsigned short ptmp[QN];
  const int b = blockIdx.x, t = threadIdx.x;

  uint32_t kb0, kb1;
  tf2x32(0u, 42u, 0u, (uint32_t)b, kb0, kb1);

  for (int i = t; i < QN; i += 1024) perm[i] = (unsigned short)i;
  __syncthreads();

  for (int round = 0; round < 2; ++round) {
    uint32_t nk0, nk1, sk0, sk1;
    tf2x32(kb0, kb1, 0u, 0u, nk0, nk1);
    tf2x32(kb0, kb1, 0u, 1u, sk0, sk1);
    kb0 = nk0; kb1 = nk1;
    for (int i = t; i < QN; i += 1024) {
      uint32_t y0, y1;
      tf2x32(sk0, sk1, 0u, (uint32_t)i, y0, y1);
      uint32_t bits = y0 ^ y1;
      comp[i] = ((unsigned long long)bits << 32) | (unsigned)i;
    }
    __syncthreads();
    for (int k = 2; k <= QN; k <<= 1) {
      for (int j = k >> 1; j > 0; j >>= 1) {
        for (int i = t; i < QN; i += 1024) {
          int ixj = i ^ j;
          if (ixj > i) {
            unsigned long long vi = comp[i], vj = comp[ixj];
            bool up = ((i & k) == 0);
            bool sw = up ? (vi > vj) : (vi < vj);
            if (sw) { comp[i] = vj; comp[ixj] = vi; }
          }
        }
        __syncthreads();
      }
    }
    for (int i = t; i < QN; i += 1024) ptmp[i] = perm[(unsigned)(comp[i] & 0xFFFFu)];
    __syncthreads();
    for (int i = t; i < QN; i += 1024) perm[i] = ptmp[i];
    __syncthreads();
  }

  const float4* xb = (const float4*)(x + (size_t)b * QN * DN);
  float4* cb = (float4*)(centers + (size_t)b * LN * DN);
  for (int e = t; e < LN * (DN / 4); e += 1024) {
    int row = e >> 7;
    int c = e & 127;
    cb[(size_t)row * 128 + c] = xb[(size_t)perm[row] * 128 + c];
  }
}

// fp64 row sum-of-squares
__global__ __launch_bounds__(256) void k_rowsq_d(const float* __restrict__ a,
                                                 double* __restrict__ o, int nrows) {
  int w = (blockIdx.x * 256 + threadIdx.x) >> 6;
  int lane = threadIdx.x & 63;
  if (w >= nrows) return;
  const float* row = a + (size_t)w * DN;
  double s = 0.0;
  for (int i = lane; i < DN; i += 64) { double v = (double)row[i]; s = fma(v, v, s); }
#pragma unroll
  for (int off = 32; off; off >>= 1) s += __shfl_down(s, off);
  if (lane == 0) o[w] = s;
}

// ---------------- MFMA layout probe (1 wave) ----------------
//   mode 1: D[4*(lane>>4)+reg][lane&15]
//   mode 2: D[(lane>>4)+4*reg][lane&15]
//   mode 0: neither -> VALU fallback
__global__ __launch_bounds__(64) void k_probe(int* __restrict__ flag) {
  __shared__ double xT[16][17];
  __shared__ double cT[16][17];
  const int t = threadIdx.x;
  for (int i = t; i < 256; i += 64) {
    int r = i >> 4, d = i & 15;
    xT[d][r] = (double)(r * 5 + d * 3 + 1);
    cT[d][r] = (double)(r * 2 + d * 7 + 2);
  }
  __syncthreads();
  const int kg = t >> 4, li = t & 15;
  f64x4 acc = {0.0, 0.0, 0.0, 0.0};
#pragma unroll
  for (int kk = 0; kk < 4; kk++) {
    double a  = xT[kk * 4 + kg][li];
    double bv = cT[kk * 4 + kg][li];
    acc = __builtin_amdgcn_mfma_f64_16x16x4f64(a, bv, acc, 0, 0, 0);
  }
  bool ok1 = true, ok2 = true;
#pragma unroll
  for (int d = 0; d < 4; d++) {
    int q1 = kg * 4 + d;
    int q2 = kg + 4 * d;
    double ref1 = 0.0, ref2 = 0.0;
    for (int dd = 0; dd < 16; dd++) {
      ref1 += xT[dd][q1] * cT[dd][li];
      ref2 += xT[dd][q2] * cT[dd][li];
    }
    ok1 = ok1 && (acc[d] == ref1);
    ok2 = ok2 && (acc[d] == ref2);
  }
  unsigned long long v1 = __ballot(ok1);
  unsigned long long v2 = __ballot(ok2);
  if (t == 0) *flag = (v1 == ~0ull) ? 1 : ((v2 == ~0ull) ? 2 : 0);
}

#define QT 64
// MFMA-path LDS pitches: pitch mod 16 == 5 (odd) -> staging-write c4-group
// stride 4*pitch*2 mod 32 = 8 (conflict-free writes); b64 frag reads stay at
// the 4-cyc wave minimum.
#define XPD 69    // x tile [16][69]
#define CPD 261   // c tile [16][261]
// VALU-path pitches (r5-verified)
#define DK 16
#define XLD 82
#define CLDf 260
__device__ __forceinline__ int grow(int q) { return q + ((q >> 3) << 1); }

// Arena: MFMA 16*69+16*261+320+320 = 5920 doubles; VALU 5504 doubles.
#define ARENA_D 5920

// dist -> softmax -> W, block-uniform branch on probed mode.
__global__ __launch_bounds__(256, 2) void k_assign(const float* __restrict__ x,
                                                   const float* __restrict__ centers,
                                                   const double* __restrict__ csqd,
                                                   float* __restrict__ W,
                                                   const int* __restrict__ flag) {
  __shared__ double arena[ARENA_D];
  const int mode = *flag;
  const int b = blockIdx.y, q0 = blockIdx.x * QT, t = threadIdx.x;
  const float* xb = x + ((size_t)b * QN + q0) * DN;
  const float* cb = centers + (size_t)b * LN * DN;
  const int xrow = t >> 2, xc4 = t & 3;

  if (mode != 0) {
    // ---------------- MFMA path ----------------
    double (*xT)[XPD]  = (double(*)[XPD])arena;                       // [16][69]
    double (*cT)[CPD]  = (double(*)[CPD])(arena + 16 * XPD);          // [16][261]
    double (*redm)[5]  = (double(*)[5])(arena + 16 * XPD + 16 * CPD); // [64][5]
    double (*reds)[5]  = (double(*)[5])(arena + 16 * XPD + 16 * CPD + 320);
    const int w = t >> 6, lane = t & 63;
    const int kg = lane >> 4, li = lane & 15;

    f64x4 acc[4][4];
#pragma unroll
    for (int i = 0; i < 4; i++)
#pragma unroll
      for (int j = 0; j < 4; j++) acc[i][j] = (f64x4){0.0, 0.0, 0.0, 0.0};

    float4 gx, gc[4];
    gx = *(const float4*)(xb + (size_t)xrow * DN + xc4 * 4);
#pragma unroll
    for (int i = 0; i < 4; i++) {
      int f = t + 256 * i; int row = f >> 2, c4 = f & 3;
      gc[i] = *(const float4*)(cb + (size_t)row * DN + c4 * 4);
    }

    for (int d0 = 0; d0 < DN; d0 += 16) {
      xT[xc4 * 4 + 0][xrow] = (double)gx.x;
      xT[xc4 * 4 + 1][xrow] = (double)gx.y;
      xT[xc4 * 4 + 2][xrow] = (double)gx.z;
      xT[xc4 * 4 + 3][xrow] = (double)gx.w;
#pragma unroll
      for (int i = 0; i < 4; i++) {
        int f = t + 256 * i; int row = f >> 2, c4 = f & 3;
        cT[c4 * 4 + 0][row] = (double)gc[i].x;
        cT[c4 * 4 + 1][row] = (double)gc[i].y;
        cT[c4 * 4 + 2][row] = (double)gc[i].z;
        cT[c4 * 4 + 3][row] = (double)gc[i].w;
      }
      __syncthreads();
      if (d0 + 16 < DN) {
        gx = *(const float4*)(xb + (size_t)xrow * DN + (d0 + 16) + xc4 * 4);
#pragma unroll
        for (int i = 0; i < 4; i++) {
          int f = t + 256 * i; int row = f >> 2, c4 = f & 3;
          gc[i] = *(const float4*)(cb + (size_t)row * DN + (d0 + 16) + c4 * 4);
        }
      }
      // register-double-buffered fragment pipeline
      double a0[4], b0[4];
#pragma unroll
      for (int qt = 0; qt < 4; qt++) a0[qt] = xT[kg][qt * 16 + li];
#pragma unroll
      for (int lt = 0; lt < 4; lt++) b0[lt] = cT[kg][w * 64 + lt * 16 + li];
#pragma unroll
      for (int kk = 0; kk < 4; kk++) {
        double a1[4], b1[4];
        if (kk + 1 < 4) {
#pragma unroll
          for (int qt = 0; qt < 4; qt++) a1[qt] = xT[(kk + 1) * 4 + kg][qt * 16 + li];
#pragma unroll
          for (int lt = 0; lt < 4; lt++) b1[lt] = cT[(kk + 1) * 4 + kg][w * 64 + lt * 16 + li];
        }
#pragma unroll
        for (int qt = 0; qt < 4; qt++)
#pragma unroll
          for (int lt = 0; lt < 4; lt++)
            acc[qt][lt] = __builtin_amdgcn_mfma_f64_16x16x4f64(a0[qt], b0[lt], acc[qt][lt], 0, 0, 0);
        if (kk + 1 < 4) {
#pragma unroll
          for (int qt = 0; qt < 4; qt++) a0[qt] = a1[qt];
#pragma unroll
          for (int lt = 0; lt < 4; lt++) b0[lt] = b1[lt];
        }
      }
      __syncthreads();
    }

    // epilogue: logits, cross-wave softmax (l split across waves)
    double csqv[4];
#pragma unroll
    for (int lt = 0; lt < 4; lt++) csqv[lt] = csqd[b * LN + w * 64 + lt * 16 + li];

    double rm[4][4];
#pragma unroll
    for (int qt = 0; qt < 4; qt++)
#pragma unroll
      for (int d = 0; d < 4; d++) {
        double m = -1e300;
#pragma unroll
        for (int lt = 0; lt < 4; lt++) {
          double lg = -5.0 * (csqv[lt] - 2.0 * acc[qt][lt][d]);
          acc[qt][lt][d] = lg;
          m = fmax(m, lg);
        }
        rm[qt][d] = m;
      }
#pragma unroll
    for (int off = 1; off < 16; off <<= 1)
#pragma unroll
      for (int qt = 0; qt < 4; qt++)
#pragma unroll
        for (int d = 0; d < 4; d++) rm[qt][d] = fmax(rm[qt][d], __shfl_xor(rm[qt][d], off, 64));
    if (li == 0) {
#pragma unroll
      for (int qt = 0; qt < 4; qt++)
#pragma unroll
        for (int d = 0; d < 4; d++) {
          int qr = qt * 16 + ((mode == 1) ? (kg * 4 + d) : (kg + 4 * d));
          redm[qr][w] = rm[qt][d];
        }
    }
    __syncthreads();
#pragma unroll
    for (int qt = 0; qt < 4; qt++)
#pragma unroll
      for (int d = 0; d < 4; d++) {
        int qr = qt * 16 + ((mode == 1) ? (kg * 4 + d) : (kg + 4 * d));
        rm[qt][d] = fmax(fmax(redm[qr][0], redm[qr][1]), fmax(redm[qr][2], redm[qr][3]));
      }
    double sv[4][4];
#pragma unroll
    for (int qt = 0; qt < 4; qt++)
#pragma unroll
      for (int d = 0; d < 4; d++) {
        double s = 0.0;
#pragma unroll
        for (int lt = 0; lt < 4; lt++) {
          double e = exp(acc[qt][lt][d] - rm[qt][d]);
          acc[qt][lt][d] = e;
          s += e;
        }
        sv[qt][d] = s;
      }
#pragma unroll
    for (int off = 1; off < 16; off <<= 1)
#pragma unroll
      for (int qt = 0; qt < 4; qt++)
#pragma unroll
        for (int d = 0; d < 4; d++) sv[qt][d] += __shfl_xor(sv[qt][d], off, 64);
    if (li == 0) {
#pragma unroll
      for (int qt = 0; qt < 4; qt++)
#pragma unroll
        for (int d = 0; d < 4; d++) {
          int qr = qt * 16 + ((mode == 1) ? (kg * 4 + d) : (kg + 4 * d));
          reds[qr][w] = sv[qt][d];
        }
    }
    __syncthreads();
#pragma unroll
    for (int qt = 0; qt < 4; qt++)
#pragma unroll
      for (int d = 0; d < 4; d++) {
        int qr = qt * 16 + ((mode == 1) ? (kg * 4 + d) : (kg + 4 * d));
        double tot = reds[qr][0] + reds[qr][1] + reds[qr][2] + reds[qr][3];
        double inv = 1.0 / tot;
        float* wr = W + ((size_t)b * QN + q0 + qr) * LN + w * 64 + li;
#pragma unroll
        for (int lt = 0; lt < 4; lt++)
          wr[lt * 16] = (float)(acc[qt][lt][d] * inv);
      }
  } else {
    // ---------------- VALU fallback (r5-verified) ----------------
    double (*xsD)[XLD]  = (double(*)[XLD])arena;
    float  (*csF)[CLDf] = (float(*)[CLDf])(arena + 16 * XLD);
    double (*red)[33]   = (double(*)[33])(arena + 16 * XLD + (16 * CLDf) / 2);
    const int rg = t & 7, cg = t >> 3;
    double acc[8][8];
#pragma unroll
    for (int i = 0; i < 8; i++)
#pragma unroll
      for (int j = 0; j < 8; j++) acc[i][j] = 0.0;

    const int xg = grow(xrow);
    float4 gx, gc[4];
    gx = *(const float4*)(xb + (size_t)xrow * DN + xc4 * 4);
#pragma unroll
    for (int i = 0; i < 4; i++) {
      int f = t + 256 * i; int row = f >> 2, c4 = f & 3;
      gc[i] = *(const float4*)(cb + (size_t)row * DN + c4 * 4);
    }

    for (int d0 = 0; d0 < DN; d0 += DK) {
      xsD[xc4 * 4 + 0][xg] = (double)gx.x; xsD[xc4 * 4 + 1][xg] = (double)gx.y;
      xsD[xc4 * 4 + 2][xg] = (double)gx.z; xsD[xc4 * 4 + 3][xg] = (double)gx.w;
#pragma unroll
      for (int i = 0; i < 4; i++) {
        int f = t + 256 * i; int row = f >> 2, c4 = f & 3;
        csF[c4 * 4 + 0][row] = gc[i].x; csF[c4 * 4 + 1][row] = gc[i].y;
        csF[c4 * 4 + 2][row] = gc[i].z; csF[c4 * 4 + 3][row] = gc[i].w;
      }
      __syncthreads();
      if (d0 + DK < DN) {
        gx = *(const float4*)(xb + (size_t)xrow * DN + (d0 + DK) + xc4 * 4);
#pragma unroll
        for (int i = 0; i < 4; i++) {
          int f = t + 256 * i; int row = f >> 2, c4 = f & 3;
          gc[i] = *(const float4*)(cb + (size_t)row * DN + (d0 + DK) + c4 * 4);
        }
      }
      double xva[8]; float4 ca0, ca1;
#pragma unroll
      for (int j = 0; j < 8; j++) xva[j] = xsD[0][rg * 10 + j];
      ca0 = *(const float4*)&csF[0][cg * 8];
      ca1 = *(const float4*)&csF[0][cg * 8 + 4];
#pragma unroll
      for (int k = 0; k < DK; k++) {
        double xvb[8]; float4 cb0, cb1;
        if (k + 1 < DK) {
#pragma unroll
          for (int j = 0; j < 8; j++) xvb[j] = xsD[k + 1][rg * 10 + j];
          cb0 = *(const float4*)&csF[k + 1][cg * 8];
          cb1 = *(const float4*)&csF[k + 1][cg * 8 + 4];
        }
        double cv[8] = {(double)ca0.x, (double)ca0.y, (double)ca0.z, (double)ca0.w,
                        (double)ca1.x, (double)ca1.y, (double)ca1.z, (double)ca1.w};
#pragma unroll
        for (int i = 0; i < 8; i++)
#pragma unroll
          for (int j = 0; j < 8; j++)
            acc[i][j] = fma(xva[i], cv[j], acc[i][j]);
        if (k + 1 < DK) {
#pragma unroll
          for (int j = 0; j < 8; j++) xva[j] = xvb[j];
          ca0 = cb0; ca1 = cb1;
        }
      }
      __syncthreads();
    }

    double csqv[8];
#pragma unroll
    for (int j = 0; j < 8; j++) csqv[j] = csqd[b * LN + cg * 8 + j];

    double lmax[8];
#pragma unroll
    for (int i = 0; i < 8; i++) {
      double m = -1e300;
#pragma unroll
      for (int j = 0; j < 8; j++) {
        double lg = -5.0 * (csqv[j] - 2.0 * acc[i][j]);
        acc[i][j] = lg;
        m = fmax(m, lg);
      }
      lmax[i] = m;
    }
#pragma unroll
    for (int i = 0; i < 8; i++) red[rg * 8 + i][cg] = lmax[i];
    __syncthreads();
    double rmax[8];
#pragma unroll
    for (int i = 0; i < 8; i++) {
      double m = -1e300;
      for (int c = 0; c < 32; c++) m = fmax(m, red[rg * 8 + i][c]);
      rmax[i] = m;
    }
    __syncthreads();
#pragma unroll
    for (int i = 0; i < 8; i++) {
      double s = 0.0;
#pragma unroll
      for (int j = 0; j < 8; j++) {
        double e = exp(acc[i][j] - rmax[i]);
        acc[i][j] = e;
        s += e;
      }
      red[rg * 8 + i][cg] = s;
    }
    __syncthreads();
#pragma unroll
    for (int i = 0; i < 8; i++) {
      double s = 0.0;
      for (int c = 0; c < 32; c++) s += red[rg * 8 + i][c];
      float* wrow = W + ((size_t)b * QN + q0 + rg * 8 + i) * LN + cg * 8;
      float4 v0 = make_float4((float)(acc[i][0] / s), (float)(acc[i][1] / s),
                              (float)(acc[i][2] / s), (float)(acc[i][3] / s));
      float4 v1 = make_float4((float)(acc[i][4] / s), (float)(acc[i][5] / s),
                              (float)(acc[i][6] / s), (float)(acc[i][7] / s));
      *(float4*)wrow = v0;
      *(float4*)(wrow + 4) = v1;
    }
  }
}

// ---------------- split-K centroid update ----------------
#define NCH 8
#define CHQ (QN / NCH)   // 512
#define UKQ 16

__global__ __launch_bounds__(256, 3) void k_update_split(
    const float* __restrict__ W, const float* __restrict__ x,
    float* __restrict__ P, float* __restrict__ dsum) {
  __shared__ float wT[UKQ][132];
  __shared__ float xT[UKQ][132];
  const int b = blockIdx.z;
  const int s = blockIdx.y;
  const int lt = (blockIdx.x >> 2) * 128;
  const int dt = (blockIdx.x & 3) * 128;
  const int t = threadIdx.x;
  const int tr = t >> 4, tc = t & 15;
  float acc[8][8];
#pragma unroll
  for (int i = 0; i < 8; i++)
#pragma unroll
    for (int j = 0; j < 8; j++) acc[i][j] = 0.f;
  float dsm[8] = {0, 0, 0, 0, 0, 0, 0, 0};

  const float* Wb = W + ((size_t)b * QN + (size_t)s * CHQ) * LN + lt;
  const float* xb = x + ((size_t)b * QN + (size_t)s * CHQ) * DN + dt;

  float4 gw[2], gx2[2];
#pragma unroll
  for (int i = 0; i < 2; i++) {
    int f = t + 256 * i; int row = f >> 5, c = f & 31;
    gw[i]  = *(const float4*)(Wb + (size_t)row * LN + c * 4);
    gx2[i] = *(const float4*)(xb + (size_t)row * DN + c * 4);
  }

  for (int k0 = 0; k0 < CHQ; k0 += UKQ) {
#pragma unroll
    for (int i = 0; i < 2; i++) {
      int f = t + 256 * i; int row = f >> 5, c = f & 31;
      *(float4*)&wT[row][c * 4] = gw[i];
      *(float4*)&xT[row][c * 4] = gx2[i];
    }
    __syncthreads();
    if (k0 + UKQ < CHQ) {
#pragma unroll
      for (int i = 0; i < 2; i++) {
        int f = t + 256 * i; int row = f >> 5, c = f & 31;
        gw[i]  = *(const float4*)(Wb + (size_t)(k0 + UKQ + row) * LN + c * 4);
        gx2[i] = *(const float4*)(xb + (size_t)(k0 + UKQ + row) * DN + c * 4);
      }
    }
#pragma unroll
    for (int k = 0; k < UKQ; k++) {
      float4 w0 = *(const float4*)&wT[k][tr * 4];
      float4 w1 = *(const float4*)&wT[k][64 + tr * 4];
      float4 x0 = *(const float4*)&xT[k][tc * 4];
      float4 x1 = *(const float4*)&xT[k][64 + tc * 4];
      float wf[8] = {w0.x, w0.y, w0.z, w0.w, w1.x, w1.y, w1.z, w1.w};
      float xf[8] = {x0.x, x0.y, x0.z, x0.w, x1.x, x1.y, x1.z, x1.w};
#pragma unroll
      for (int i = 0; i < 8; i++) {
        dsm[i] += wf[i];
#pragma unroll
        for (int j = 0; j < 8; j++) acc[i][j] = fmaf(wf[i], xf[j], acc[i][j]);
      }
    }
    __syncthreads();
  }

#pragma unroll
  for (int i = 0; i < 8; i++) {
    int l = lt + ((i < 4) ? (tr * 4 + i) : (64 + tr * 4 + i - 4));
    float* prow = P + (((size_t)s * RB + b) * LN + l) * DN + dt;
    *(float4*)(prow + tc * 4)      = make_float4(acc[i][0], acc[i][1], acc[i][2], acc[i][3]);
    *(float4*)(prow + 64 + tc * 4) = make_float4(acc[i][4], acc[i][5], acc[i][6], acc[i][7]);
    if (tc == 0) dsum[((size_t)s * RB + b) * LN + l] = dsm[i];
  }
}

// Cnew = (sum_s P) / (sum_s dsum + eps); fused fp64 row sumsq -> csqd
__global__ __launch_bounds__(128) void k_reduce(const float* __restrict__ P,
                                                const float* __restrict__ dsum,
                                                float* __restrict__ cnew,
                                                double* __restrict__ csqd) {
  const int row = blockIdx.x;          // b*LN + l
  const int b = row >> 8, l = row & 255;
  const int t = threadIdx.x;
  float dn = 0.f;
#pragma unroll
  for (int s = 0; s < NCH; s++) dn += dsum[((size_t)s * RB + b) * LN + l];
  float den = dn + 1e-9f;
  float4 v = make_float4(0.f, 0.f, 0.f, 0.f);
#pragma unroll
  for (int s = 0; s < NCH; s++) {
    float4 p = *(const float4*)(P + (((size_t)s * RB + b) * LN + l) * DN + t * 4);
    v.x += p.x; v.y += p.y; v.z += p.z; v.w += p.w;
  }
  float4 o = make_float4(v.x / den, v.y / den, v.z / den, v.w / den);
  *(float4*)(cnew + ((size_t)b * LN + l) * DN + t * 4) = o;
  double sq = (double)o.x * o.x + (double)o.y * o.y +
              (double)o.z * o.z + (double)o.w * o.w;
#pragma unroll
  for (int off = 32; off; off >>= 1) sq += __shfl_down(sq, off);
  __shared__ double sred[2];
  if ((t & 63) == 0) sred[t >> 6] = sq;
  __syncthreads();
  if (t == 0) csqd[row] = sred[0] + sred[1];
}

// monolithic fallback update (used when ws is small)
#define LT 64
#define DT 64
#define KQ 32
__global__ __launch_bounds__(256) void k_update_mono(const float* __restrict__ W,
                                                     const float* __restrict__ x,
                                                     float* __restrict__ cnew) {
  __shared__ float wT[KQ][LT + 4];
  __shared__ float xT[KQ][DT + 4];
  const int b = blockIdx.z;
  const int l0 = blockIdx.x * LT;
  const int d0 = blockIdx.y * DT;
  const int t = threadIdx.x;
  const int rg = t & 15;
  const int cg = t >> 4;
  float acc[4][4];
#pragma unroll
  for (int i = 0; i < 4; i++)
#pragma unroll
    for (int j = 0; j < 4; j++) acc[i][j] = 0.f;
  float dsm[4] = {0.f, 0.f, 0.f, 0.f};
  const float* Wb = W + (size_t)b * QN * LN;
  const float* xb = x + (size_t)b * QN * DN;
  for (int k0 = 0; k0 < QN; k0 += KQ) {
#pragma unroll
    for (int i = 0; i < 2; i++) {
      int f = t + 256 * i;
      int row = f >> 4, c4 = f & 15;
      *(float4*)&wT[row][c4 * 4] = *(const float4*)(Wb + (size_t)(k0 + row) * LN + l0 + c4 * 4);
    }
#pragma unroll
    for (int i = 0; i < 2; i++) {
      int f = t + 256 * i;
      int row = f >> 4, c4 = f & 15;
      *(float4*)&xT[row][c4 * 4] = *(const float4*)(xb + (size_t)(k0 + row) * DN + d0 + c4 * 4);
    }
    __syncthreads();
#pragma unroll
    for (int k = 0; k < KQ; k++) {
      float wf[4], xf[4];
      *(float4*)wf = *(const float4*)&wT[k][rg * 4];
      *(float4*)xf = *(const float4*)&xT[k][cg * 4];
#pragma unroll
      for (int i = 0; i < 4; i++) {
        dsm[i] += wf[i];
#pragma unroll
        for (int j = 0; j < 4; j++) acc[i][j] = fmaf(wf[i], xf[j], acc[i][j]);
      }
    }
    __syncthreads();
  }
#pragma unroll
  for (int i = 0; i < 4; i++) {
    float den = dsm[i] + 1e-9f;
    *(float4*)(cnew + ((size_t)b * LN + l0 + rg * 4 + i) * DN + d0 + cg * 4) =
        make_float4(acc[i][0] / den, acc[i][1] / den, acc[i][2] / den, acc[i][3] / den);
  }
}

// fp64 dist -> argmin -> gather; MFMA path (probe-gated) + VALU fallback.
// Arena: MFMA 16*69+16*261+320+160+16 = 5776; VALU 1312+2080+2112+528+16 = 6048.
#define ARENA_F 6048
__global__ __launch_bounds__(256, 2) void k_final(const float* __restrict__ x,
                                                  const float* __restrict__ centers,
                                                  const double* __restrict__ csqd,
                                                  float* __restrict__ out,
                                                  const int* __restrict__ flag) {
  __shared__ double arena[ARENA_F];
  const int mode = *flag;
  const int b = blockIdx.y, q0 = blockIdx.x * QT, t = threadIdx.x;
  const float* xb = x + ((size_t)b * QN + q0) * DN;
  const float* cb = centers + (size_t)b * LN * DN;
  const int xrow = t >> 2, xc4 = t & 3;

  if (mode != 0) {
    // ---------------- MFMA path ----------------
    double (*xT)[XPD] = (double(*)[XPD])arena;
    double (*cT)[CPD] = (double(*)[CPD])(arena + 16 * XPD);
    double (*redv)[5] = (double(*)[5])(arena + 16 * XPD + 16 * CPD);          // [64][5]
    int*    redi      = (int*)(arena + 16 * XPD + 16 * CPD + 320);            // [64][5]
    unsigned short* labels = (unsigned short*)(arena + 16 * XPD + 16 * CPD + 480);
    const int w = t >> 6, lane = t & 63;
    const int kg = lane >> 4, li = lane & 15;

    f64x4 acc[4][4];
#pragma unroll
    for (int i = 0; i < 4; i++)
#pragma unroll
      for (int j = 0; j < 4; j++) acc[i][j] = (f64x4){0.0, 0.0, 0.0, 0.0};

    float4 gx, gc[4];
    gx = *(const float4*)(xb + (size_t)xrow * DN + xc4 * 4);
#pragma unroll
    for (int i = 0; i < 4; i++) {
      int f = t + 256 * i; int row = f >> 2, c4 = f & 3;
      gc[i] = *(const float4*)(cb + (size_t)row * DN + c4 * 4);
    }

    for (int d0 = 0; d0 < DN; d0 += 16) {
      xT[xc4 * 4 + 0][xrow] = (double)gx.x;
      xT[xc4 * 4 + 1][xrow] = (double)gx.y;
      xT[xc4 * 4 + 2][xrow] = (double)gx.z;
      xT[xc4 * 4 + 3][xrow] = (double)gx.w;
#pragma unroll
      for (int i = 0; i < 4; i++) {
        int f = t + 256 * i; int row = f >> 2, c4 = f & 3;
        cT[c4 * 4 + 0][row] = (double)gc[i].x;
        cT[c4 * 4 + 1][row] = (double)gc[i].y;
        cT[c4 * 4 + 2][row] = (double)gc[i].z;
        cT[c4 * 4 + 3][row] = (double)gc[i].w;
      }
      __syncthreads();
      if (d0 + 16 < DN) {
        gx = *(const float4*)(xb + (size_t)xrow * DN + (d0 + 16) + xc4 * 4);
#pragma unroll
        for (int i = 0; i < 4; i++) {
          int f = t + 256 * i; int row = f >> 2, c4 = f & 3;
          gc[i] = *(const float4*)(cb + (size_t)row * DN + (d0 + 16) + c4 * 4);
        }
      }
      double a0[4], b0[4];
#pragma unroll
      for (int qt = 0; qt < 4; qt++) a0[qt] = xT[kg][qt * 16 + li];
#pragma unroll
      for (int lt = 0; lt < 4; lt++) b0[lt] = cT[kg][w * 64 + lt * 16 + li];
#pragma unroll
      for (int kk = 0; kk < 4; kk++) {
        double a1[4], b1[4];
        if (kk + 1 < 4) {
#pragma unroll
          for (int qt = 0; qt < 4; qt++) a1[qt] = xT[(kk + 1) * 4 + kg][qt * 16 + li];
#pragma unroll
          for (int lt = 0; lt < 4; lt++) b1[lt] = cT[(kk + 1) * 4 + kg][w * 64 + lt * 16 + li];
        }
#pragma unroll
        for (int qt = 0; qt < 4; qt++)
#pragma unroll
          for (int lt = 0; lt < 4; lt++)
            acc[qt][lt] = __builtin_amdgcn_mfma_f64_16x16x4f64(a0[qt], b0[lt], acc[qt][lt], 0, 0, 0);
        if (kk + 1 < 4) {
#pragma unroll
          for (int qt = 0; qt < 4; qt++) a0[qt] = a1[qt];
#pragma unroll
          for (int lt = 0; lt < 4; lt++) b0[lt] = b1[lt];
        }
      }
      __syncthreads();
    }

    // argmin epilogue: key = csq - 2*dot; first-min tie-break on l
    double csqv[4];
#pragma unroll
    for (int lt = 0; lt < 4; lt++) csqv[lt] = csqd[b * LN + w * 64 + lt * 16 + li];

    double bv[4][4]; int bi[4][4];
#pragma unroll
    for (int qt = 0; qt < 4; qt++)
#pragma unroll
      for (int d = 0; d < 4; d++) {
        double best = 1e300; int bidx = 0;
#pragma unroll
        for (int lt = 0; lt < 4; lt++) {
          double dd = csqv[lt] - 2.0 * acc[qt][lt][d];
          int l = w * 64 + lt * 16 + li;
          if (dd < best) { best = dd; bidx = l; }
        }
        bv[qt][d] = best; bi[qt][d] = bidx;
      }
#pragma unroll
    for (int off = 1; off < 16; off <<= 1)
#pragma unroll
      for (int qt = 0; qt < 4; qt++)
#pragma unroll
        for (int d = 0; d < 4; d++) {
          double ov = __shfl_xor(bv[qt][d], off, 64);
          int oi = __shfl_xor(bi[qt][d], off, 64);
          if (ov < bv[qt][d] || (ov == bv[qt][d] && oi < bi[qt][d])) {
            bv[qt][d] = ov; bi[qt][d] = oi;
          }
        }
    if (li == 0) {
#pragma unroll
      for (int qt = 0; qt < 4; qt++)
#pragma unroll
        for (int d = 0; d < 4; d++) {
          int qr = qt * 16 + ((mode == 1) ? (kg * 4 + d) : (kg + 4 * d));
          redv[qr][w] = bv[qt][d];
          redi[qr * 5 + w] = bi[qt][d];
        }
    }
    __syncthreads();
    if (t < QT) {
      double best = redv[t][0]; int bidx = redi[t * 5 + 0];
#pragma unroll
      for (int ww = 1; ww < 4; ww++) {
        double v = redv[t][ww]; int id = redi[t * 5 + ww];
        if (v < best || (v == best && id < bidx)) { best = v; bidx = id; }
      }
      labels[t] = (unsigned short)bidx;
    }
    __syncthreads();
    const float4* cb4 = (const float4*)(centers + (size_t)b * LN * DN);
    float4* ob = (float4*)(out + ((size_t)b * QN + q0) * DN);
    for (int e = t; e < QT * (DN / 4); e += 256) {
      int row = e >> 7, c = e & 127;
      ob[(size_t)row * 128 + c] = cb4[(size_t)labels[row] * 128 + c];
    }
  } else {
    // ---------------- VALU fallback (r5-verified) ----------------
    double (*xsD)[XLD]  = (double(*)[XLD])arena;                       // 1312
    float  (*csF)[CLDf] = (float(*)[CLDf])(arena + 16 * XLD);          // 2080
    double (*redv)[33]  = (double(*)[33])(arena + 3392);               // 2112
    unsigned short* redi = (unsigned short*)(arena + 5504);            // 528
    unsigned short* labels = (unsigned short*)(arena + 6032);          // 16
    const int rg = t & 7, cg = t >> 3;
    double acc[8][8];
#pragma unroll
    for (int i = 0; i < 8; i++)
#pragma unroll
      for (int j = 0; j < 8; j++) acc[i][j] = 0.0;

    const int xg = grow(xrow);
    float4 gx, gc[4];
    gx = *(const float4*)(xb + (size_t)xrow * DN + xc4 * 4);
#pragma unroll
    for (int i = 0; i < 4; i++) {
      int f = t + 256 * i; int row = f >> 2, c4 = f & 3;
      gc[i] = *(const float4*)(cb + (size_t)row * DN + c4 * 4);
    }

    for (int d0 = 0; d0 < DN; d0 += DK) {
      xsD[xc4 * 4 + 0][xg] = (double)gx.x; xsD[xc4 * 4 + 1][xg] = (double)gx.y;
      xsD[xc4 * 4 + 2][xg] = (double)gx.z; xsD[xc4 * 4 + 3][xg] = (double)gx.w;
#pragma unroll
      for (int i = 0; i < 4; i++) {
        int f = t + 256 * i; int row = f >> 2, c4 = f & 3;
        csF[c4 * 4 + 0][row] = gc[i].x; csF[c4 * 4 + 1][row] = gc[i].y;
        csF[c4 * 4 + 2][row] = gc[i].z; csF[c4 * 4 + 3][row] = gc[i].w;
      }
      __syncthreads();
      if (d0 + DK < DN) {
        gx = *(const float4*)(xb + (size_t)xrow * DN + (d0 + DK) + xc4 * 4);
#pragma unroll
        for (int i = 0; i < 4; i++) {
          int f = t + 256 * i; int row = f >> 2, c4 = f & 3;
          gc[i] = *(const float4*)(cb + (size_t)row * DN + (d0 + DK) + c4 * 4);
        }
      }
      double xva[8]; float4 ca0, ca1;
#pragma unroll
      for (int j = 0; j < 8; j++) xva[j] = xsD[0][rg * 10 + j];
      ca0 = *(const float4*)&csF[0][cg * 8];
      ca1 = *(const float4*)&csF[0][cg * 8 + 4];
#pragma unroll
      for (int k = 0; k < DK; k++) {
        double xvb[8]; float4 cb0, cb1;
        if (k + 1 < DK) {
#pragma unroll
          for (int j = 0; j < 8; j++) xvb[j] = xsD[k + 1][rg * 10 + j];
          cb0 = *(const float4*)&csF[k + 1][cg * 8];
          cb1 = *(const float4*)&csF[k + 1][cg * 8 + 4];
        }
        double cv[8] = {(double)ca0.x, (double)ca0.y, (double)ca0.z, (double)ca0.w,
                        (double)ca1.x, (double)ca1.y, (double)ca1.z, (double)ca1.w};
#pragma unroll
        for (int i = 0; i < 8; i++)
#pragma unroll
          for (int j = 0; j < 8; j++)
            acc[i][j] = fma(xva[i], cv[j], acc[i][j]);
        if (k + 1 < DK) {
#pragma unroll
          for (int j = 0; j < 8; j++) xva[j] = xvb[j];
          ca0 = cb0; ca1 = cb1;
        }
      }
      __syncthreads();
    }

    double csqv[8];
#pragma unroll
    for (int j = 0; j < 8; j++) csqv[j] = csqd[b * LN + cg * 8 + j];

    double bv[8]; int bi[8];
#pragma unroll
    for (int i = 0; i < 8; i++) {
      bv[i] = 1e300; bi[i] = 0;
#pragma unroll
      for (int j = 0; j < 8; j++) {
        double dd = csqv[j] - 2.0 * acc[i][j];
        if (dd < bv[i]) { bv[i] = dd; bi[i] = cg * 8 + j; }
      }
    }
#pragma unroll
    for (int i = 0; i < 8; i++) {
      redv[rg * 8 + i][cg] = bv[i];
      redi[(rg * 8 + i) * 33 + cg] = (unsigned short)bi[i];
    }
    __syncthreads();
    if (t < QT) {
      double best = 1e300; int bidx = 0;
      for (int c = 0; c < 32; c++) {
        double v = redv[t][c];
        int id = redi[t * 33 + c];
        if (v < best || (v == best && id < bidx)) { best = v; bidx = id; }
      }
      labels[t] = (unsigned short)bidx;
    }
    __syncthreads();
    const float4* cb4 = (const float4*)(centers + (size_t)b * LN * DN);
    float4* ob = (float4*)(out + ((size_t)b * QN + q0) * DN);
    for (int e = t; e < QT * (DN / 4); e += 256) {
      int row = e >> 7, c = e & 127;
      ob[(size_t)row * 128 + c] = cb4[(size_t)labels[row] * 128 + c];
    }
  }
}

extern "C" void kernel_launch(void* const* d_in, const int* in_sizes, int n_in,
                              void* d_out, int out_size, void* d_ws, size_t ws_size,
                              hipStream_t stream) {
  const float* x = (const float*)d_in[0];
  float* out = (float*)d_out;

  const size_t szC    = (size_t)RB * LN * DN * sizeof(float);     // 4 MB
  const size_t szCsqD = (size_t)RB * LN * sizeof(double);         // 16 KB
  const size_t szDsum = (size_t)NCH * RB * LN * sizeof(float);    // 64 KB
  const size_t szFlag = 256;
  const size_t szW    = (size_t)RB * QN * LN * sizeof(float);     // 33.5 MB

  char* p = (char*)d_ws;
  float*  cA   = (float*)p;  p += szC;
  float*  cB   = (float*)p;  p += szC;
  double* csqd = (double*)p; p += szCsqD;
  float*  dsum = (float*)p;  p += szDsum;
  int*    flag = (int*)p;    p += szFlag;
  const bool bigws = ws_size >= 2 * szC + szCsqD + szDsum + szFlag + szW;
  float* W = bigws ? (float*)p : (float*)d_out;
  float* P = (float*)d_out;   // split-K partials live in d_out (k_final rewrites)

  k_probe<<<1, 64, 0, stream>>>(flag);
  k_init<<<RB, 1024, 0, stream>>>(x, cA);
  k_rowsq_d<<<(RB * LN) / 4, 256, 0, stream>>>(cA, csqd, RB * LN);

  float* cur = cA;
  float* nxt = cB;
  for (int it = 0; it < NITERS; ++it) {
    k_assign<<<dim3(QN / QT, RB), 256, 0, stream>>>(x, cur, csqd, W, flag);
    if (bigws) {
      k_update_split<<<dim3(8, NCH, RB), 256, 0, stream>>>(W, x, P, dsum);
      k_reduce<<<RB * LN, 128, 0, stream>>>(P, dsum, nxt, csqd);
    } else {
      k_update_mono<<<dim3(LN / LT, DN / DT, RB), 256, 0, stream>>>(W, x, nxt);
      k_rowsq_d<<<(RB * LN) / 4, 256, 0, stream>>>(nxt, csqd, RB * LN);
    }
    float* tmp = cur; cur = nxt; nxt = tmp;
  }
  k_final<<<dim3(QN / QT, RB), 256, 0, stream>>>(x, cur, csqd, out, flag);
}